// Round 1
// baseline (128.907 us; speedup 1.0000x reference)
//
#include <hip/hip_runtime.h>

#define G 64
#define C 32
#define D 18432
#define NCH 18          // column chunks for K1
#define TD 1024         // cols per K1 block  (NCH*TD == D)
#define TDI 64          // cols per LDS sub-tile
#define EPS 1e-5f
#define NS_ITERS 5

// ---------------------------------------------------------------------------
// K1: per (group, chunk): partial Gram  P = Z_chunk * Z_chunk^T  (32x32)
//     and partial row sums (32). Deterministic (no atomics).
// ---------------------------------------------------------------------------
__global__ __launch_bounds__(256) void k1_gram(const float* __restrict__ W,
                                               float* __restrict__ psum,
                                               float* __restrict__ prow) {
    __shared__ float tile[TDI][C + 1];   // transposed tile, padded
    __shared__ float red[4][C * C];      // per-wave partial 32x32

    const int bid  = blockIdx.x;
    const int g    = bid / NCH;
    const int ch   = bid % NCH;
    const int tid  = threadIdx.x;
    const int lane = tid & 63;
    const int wave = tid >> 6;
    const float* Zg = W + (size_t)g * C * D + (size_t)ch * TD;

    // lane -> 4x4 output tile
    const int c0 = ((lane >> 3) & 7) << 2;
    const int e0 = (lane & 7) << 2;

    float acc[4][4];
#pragma unroll
    for (int a = 0; a < 4; ++a)
#pragma unroll
        for (int b = 0; b < 4; ++b) acc[a][b] = 0.f;
    float rs[8];
#pragma unroll
    for (int i = 0; i < 8; ++i) rs[i] = 0.f;

    for (int t = 0; t < TD / TDI; ++t) {
        __syncthreads();   // protect tile reuse
        // stage TDI cols x 32 rows, transposed into LDS
#pragma unroll
        for (int i = 0; i < 8; ++i) {
            int r = i * 4 + wave;
            float v = Zg[(size_t)r * D + (size_t)t * TDI + lane];
            tile[lane][r] = v;
            rs[i] += v;
        }
        __syncthreads();
        // each wave consumes its 16 columns of the sub-tile
#pragma unroll
        for (int j = 0; j < TDI / 4; ++j) {
            int d = wave * (TDI / 4) + j;
            float zc[4], ze[4];
#pragma unroll
            for (int i = 0; i < 4; ++i) zc[i] = tile[d][c0 + i];
#pragma unroll
            for (int i = 0; i < 4; ++i) ze[i] = tile[d][e0 + i];
#pragma unroll
            for (int a = 0; a < 4; ++a)
#pragma unroll
                for (int b = 0; b < 4; ++b)
                    acc[a][b] = fmaf(zc[a], ze[b], acc[a][b]);
        }
    }

    // per-wave partial -> LDS
#pragma unroll
    for (int a = 0; a < 4; ++a)
#pragma unroll
        for (int b = 0; b < 4; ++b)
            red[wave][(c0 + a) * C + (e0 + b)] = acc[a][b];

    // rowsum: all lanes of a wave hold the same rows -> wave reduce
#pragma unroll
    for (int i = 0; i < 8; ++i) {
        float v = rs[i];
#pragma unroll
        for (int off = 32; off >= 1; off >>= 1)
            v += __shfl_xor(v, off, 64);
        rs[i] = v;
    }
    if (lane == 0) {
#pragma unroll
        for (int i = 0; i < 8; ++i)
            prow[(size_t)bid * C + i * 4 + wave] = rs[i];
    }

    __syncthreads();
    // sum the 4 wave partials, store chunk partial
#pragma unroll
    for (int k = 0; k < 4; ++k) {
        int el = tid + 256 * k;
        float s = red[0][el] + red[1][el] + red[2][el] + red[3][el];
        psum[(size_t)bid * (C * C) + el] = s;
    }
}

// ---------------------------------------------------------------------------
// K2: per group: S = sum(partials) - D*m*m^T + EPS*I; normalize by Frobenius;
//     5 Newton-Schulz iterations; emit M^T (= (B/sqrt(norm))^T) and v = M*m.
// ---------------------------------------------------------------------------
__global__ __launch_bounds__(256) void k2_ns(const float* __restrict__ psum,
                                             const float* __restrict__ prow,
                                             float* __restrict__ MT,
                                             float* __restrict__ vout) {
    __shared__ float S[C][C + 1];
    __shared__ float B[C][C + 1];
    __shared__ float T1[C][C + 1];
    __shared__ float T2[C][C + 1];
    __shared__ float mean[C];
    __shared__ float redw[4];
    __shared__ float normsh;

    const int g   = blockIdx.x;
    const int tid = threadIdx.x;
    const int e   = tid & 31;
    const int cb  = tid >> 5;   // c = cb + 8k

    float selt[4];
#pragma unroll
    for (int k = 0; k < 4; ++k) {
        int el = tid + 256 * k;
        float s = 0.f;
        for (int ch = 0; ch < NCH; ++ch)
            s += psum[((size_t)g * NCH + ch) * (C * C) + el];
        selt[k] = s;
    }
    if (tid < C) {
        float s = 0.f;
        for (int ch = 0; ch < NCH; ++ch)
            s += prow[((size_t)g * NCH + ch) * C + tid];
        mean[tid] = s / (float)D;
    }
    __syncthreads();

    float ss = 0.f;
#pragma unroll
    for (int k = 0; k < 4; ++k) {
        int el = tid + 256 * k;
        int c = el >> 5;
        float sv = selt[k] - (float)D * mean[c] * mean[e];
        if (c == e) sv += EPS;
        S[c][e] = sv;
        ss = fmaf(sv, sv, ss);
    }
#pragma unroll
    for (int off = 32; off >= 1; off >>= 1) ss += __shfl_xor(ss, off, 64);
    if ((tid & 63) == 0) redw[tid >> 6] = ss;
    __syncthreads();
    if (tid == 0) normsh = sqrtf(redw[0] + redw[1] + redw[2] + redw[3]);
    __syncthreads();
    const float inv_norm = 1.0f / normsh;
#pragma unroll
    for (int k = 0; k < 4; ++k) {
        int c = cb + 8 * k;
        S[c][e] *= inv_norm;
        B[c][e] = (c == e) ? 1.f : 0.f;
    }
    __syncthreads();

    for (int it = 0; it < NS_ITERS; ++it) {
        // T1 = B@B
#pragma unroll
        for (int k = 0; k < 4; ++k) {
            int c = cb + 8 * k;
            float s = 0.f;
            for (int kk = 0; kk < C; ++kk)
                s = fmaf(B[c][kk], B[kk][e], s);
            T1[c][e] = s;
        }
        __syncthreads();
        // T2 = T1@B
#pragma unroll
        for (int k = 0; k < 4; ++k) {
            int c = cb + 8 * k;
            float s = 0.f;
            for (int kk = 0; kk < C; ++kk)
                s = fmaf(T1[c][kk], B[kk][e], s);
            T2[c][e] = s;
        }
        __syncthreads();
        // B = 1.5B - 0.5*(T2@Sn)
        float pv[4];
#pragma unroll
        for (int k = 0; k < 4; ++k) {
            int c = cb + 8 * k;
            float s = 0.f;
            for (int kk = 0; kk < C; ++kk)
                s = fmaf(T2[c][kk], S[kk][e], s);
            pv[k] = s;
        }
#pragma unroll
        for (int k = 0; k < 4; ++k) {
            int c = cb + 8 * k;
            B[c][e] = 1.5f * B[c][e] - 0.5f * pv[k];
        }
        __syncthreads();
    }

    const float invs = 1.0f / sqrtf(normsh);
#pragma unroll
    for (int k = 0; k < 4; ++k) {
        int c = cb + 8 * k;
        MT[(size_t)g * (C * C) + e * C + c] = B[c][e] * invs;
    }
    if (tid < C) {
        float s = 0.f;
        for (int ee = 0; ee < C; ++ee)
            s = fmaf(B[tid][ee] * invs, mean[ee], s);
        vout[(size_t)g * C + tid] = s;
    }
}

// ---------------------------------------------------------------------------
// K3: W_out = M * Z - v * 1^T   (per group), 2 cols per thread (float2)
// ---------------------------------------------------------------------------
__global__ __launch_bounds__(256) void k3_apply(const float* __restrict__ W,
                                                const float* __restrict__ MT,
                                                const float* __restrict__ vv,
                                                float* __restrict__ out) {
    const int blocksPerGroup = D / 512;     // 36
    const int g  = blockIdx.x / blocksPerGroup;
    const int cb = blockIdx.x % blocksPerGroup;
    const int d0 = cb * 512 + (int)threadIdx.x * 2;
    const float* Zg = W + (size_t)g * C * D + d0;
    const float* Mg = MT + (size_t)g * (C * C);

    float accx[C], accy[C];
#pragma unroll
    for (int r = 0; r < C; ++r) { accx[r] = 0.f; accy[r] = 0.f; }

    for (int e = 0; e < C; ++e) {
        float2 z = *(const float2*)(Zg + (size_t)e * D);
#pragma unroll
        for (int r = 0; r < C; ++r) {
            float m = Mg[e * C + r];   // wave-uniform -> scalar load
            accx[r] = fmaf(m, z.x, accx[r]);
            accy[r] = fmaf(m, z.y, accy[r]);
        }
    }

    float* Og = out + (size_t)g * C * D + d0;
#pragma unroll
    for (int r = 0; r < C; ++r) {
        float vr = vv[g * C + r];      // wave-uniform
        float2 o = make_float2(accx[r] - vr, accy[r] - vr);
        *(float2*)(Og + (size_t)r * D) = o;
    }
}

extern "C" void kernel_launch(void* const* d_in, const int* in_sizes, int n_in,
                              void* d_out, int out_size, void* d_ws, size_t ws_size,
                              hipStream_t stream) {
    const float* w = (const float*)d_in[0];
    float* out = (float*)d_out;

    float* psum = (float*)d_ws;                          // 1152*1024 floats
    float* prow = psum + (size_t)(G * NCH) * (C * C);    // 1152*32
    float* MT   = prow + (size_t)(G * NCH) * C;          // 64*1024
    float* vv   = MT   + (size_t)G * (C * C);            // 64*32

    k1_gram <<<G * NCH, 256, 0, stream>>>(w, psum, prow);
    k2_ns   <<<G,       256, 0, stream>>>(psum, prow, MT, vv);
    k3_apply<<<G * (D / 512), 256, 0, stream>>>(w, MT, vv, out);
}